// Round 3
// baseline (138.201 us; speedup 1.0000x reference)
//
#include <hip/hip_runtime.h>
#include <math.h>

// BinarySphericalQuantizer forward, EMBED_DIM=16, all scalars = 1.
// Outputs concatenated in d_out (float32):
//   [0, n)                : zq = sign(z)*0.25            (n = 33554432)
//   [n]                   : loss = persample_entropy - cb_entropy
//   [n+1, n+1+rows)       : indices (bit-packed signs), as float
//   [n+1+rows, +32)       : avg_prob (16 x 2)
//
// Row-per-lane: each lane owns a 16-elem row -> no cross-lane ops in hot loop.
// s = z/||z|| has |s|<=1, so sigmoid/entropy are evaluated by short even/odd
// polynomials (max err ~2e-5; only affects loss & avg_prob, thresholds ~1e-2):
//   p - 1/2   = s * g(t),  g(t) = -1/4 + t/48 - t^2/480 + 17 t^3/80640,  t=s^2
//   H - ln2   = t * (-1/8 + t/64 - t^2/576 + 119 t^4.../645120)
// Constant parts (rows*16*ln2, rows*0.5) are added exactly in the finisher.

__global__ __launch_bounds__(256) void bsq_main(
    const float* __restrict__ z,
    float* __restrict__ zq,
    float* __restrict__ idx_out,
    float* __restrict__ ws_h,      // [gridDim.x] partials of sum(H - ln2)
    float* __restrict__ ws_p,      // [16][gridDim.x] partials of sum(p - 1/2)
    long long rows)
{
    const int tid = threadIdx.x;
    const long long stride = (long long)gridDim.x * blockDim.x;

    const float C1 = -0.125f,      C2 = 1.0f/64.0f,  C3 = -1.0f/576.0f, C4 = 119.0f/645120.0f;
    const float D0 = -0.25f,       D1 = 1.0f/48.0f,  D2 = -1.0f/480.0f, D3 = 17.0f/80640.0f;

    float h_acc = 0.f;
    float sg[16];
    #pragma unroll
    for (int j = 0; j < 16; ++j) sg[j] = 0.f;

    for (long long r = (long long)blockIdx.x * blockDim.x + tid; r < rows; r += stride) {
        const float4* zr = reinterpret_cast<const float4*>(z) + (r << 2);
        float4 q0 = zr[0], q1 = zr[1], q2 = zr[2], q3 = zr[3];
        float v[16] = {q0.x,q0.y,q0.z,q0.w, q1.x,q1.y,q1.z,q1.w,
                       q2.x,q2.y,q2.z,q2.w, q3.x,q3.y,q3.z,q3.w};

        float ss = 0.f;
        #pragma unroll
        for (int j = 0; j < 16; ++j) ss = fmaf(v[j], v[j], ss);
        const float scale = rsqrtf(fmaxf(ss, 1e-24f));   // == 1/max(||z||,1e-12)

        unsigned bits = 0u;
        float o[16];
        #pragma unroll
        for (int j = 0; j < 16; ++j) {
            const float s = v[j] * scale;
            const float t = s * s;
            // p - 1/2
            const float gp = fmaf(t, fmaf(t, fmaf(t, D3, D2), D1), D0);
            sg[j] = fmaf(s, gp, sg[j]);
            // H - ln2
            const float hin = fmaf(t, fmaf(t, fmaf(t, C4, C3), C2), C1);
            h_acc = fmaf(t, hin, h_acc);

            const bool bit = v[j] > 0.0f;
            o[j] = bit ? 0.25f : -0.25f;
            bits |= (bit ? 1u : 0u) << (15 - j);
        }

        float4* zo = reinterpret_cast<float4*>(zq) + (r << 2);
        zo[0] = make_float4(o[0],o[1],o[2],o[3]);
        zo[1] = make_float4(o[4],o[5],o[6],o[7]);
        zo[2] = make_float4(o[8],o[9],o[10],o[11]);
        zo[3] = make_float4(o[12],o[13],o[14],o[15]);
        idx_out[r] = (float)bits;          // <= 65535, exact in f32; coalesced
    }

    // end-of-kernel reductions (cold path)
    #pragma unroll
    for (int m = 32; m >= 1; m >>= 1) {
        h_acc += __shfl_xor(h_acc, m);
        #pragma unroll
        for (int j = 0; j < 16; ++j) sg[j] += __shfl_xor(sg[j], m);
    }

    __shared__ float sh_h[4];
    __shared__ float sh_p[4][16];
    const int wave = tid >> 6;
    const int lane = tid & 63;
    if (lane == 0) {
        sh_h[wave] = h_acc;
        #pragma unroll
        for (int j = 0; j < 16; ++j) sh_p[wave][j] = sg[j];
    }
    __syncthreads();

    if (tid == 0)
        ws_h[blockIdx.x] = sh_h[0] + sh_h[1] + sh_h[2] + sh_h[3];
    if (tid < 16)
        ws_p[(long long)tid * gridDim.x + blockIdx.x] =
            sh_p[0][tid] + sh_p[1][tid] + sh_p[2][tid] + sh_p[3][tid];
}

// 16 waves: wave w reduces p-group w; wave 0 also reduces h.
__global__ __launch_bounds__(1024) void bsq_final(
    const float* __restrict__ ws_h,
    const float* __restrict__ ws_p,
    float* __restrict__ loss_out,
    float* __restrict__ avgp_out,
    int nb, long long rows)
{
    const int tid  = threadIdx.x;
    const int wave = tid >> 6;     // 0..15
    const int lane = tid & 63;
    const double invR = 1.0 / (double)rows;
    const double LN2 = 0.6931471805599453;

    __shared__ double sh_q[16];
    __shared__ double sh_h;

    double p = 0.0;
    for (int i = lane; i < nb; i += 64)
        p += (double)ws_p[(long long)wave * nb + i];

    double h = 0.0;
    if (wave == 0)
        for (int i = lane; i < nb; i += 64)
            h += (double)ws_h[i];

    #pragma unroll
    for (int m = 32; m >= 1; m >>= 1)
        p += __shfl_xor(p, m);
    if (wave == 0) {
        #pragma unroll
        for (int m = 32; m >= 1; m >>= 1)
            h += __shfl_xor(h, m);
        if (lane == 0) sh_h = 16.0 * LN2 + h * invR;   // persample entropy
    }
    if (lane == 0) sh_q[wave] = 0.5 + p * invR;        // avg_prob[g][0]
    __syncthreads();

    if (wave == 0) {
        const double q = (lane < 16) ? sh_q[lane] : 0.0;
        double term = 0.0;
        if (lane < 16)
            term = -(q * log(q + 1e-8) + (1.0 - q) * log((1.0 - q) + 1e-8));
        #pragma unroll
        for (int m = 32; m >= 1; m >>= 1)
            term += __shfl_xor(term, m);
        if (lane == 0)
            loss_out[0] = (float)(sh_h - term);   // GAMMA0=GAMMA=ZETA=INV_T=1
        if (lane < 16) {
            avgp_out[2 * lane]     = (float)sh_q[lane];
            avgp_out[2 * lane + 1] = (float)(1.0 - sh_q[lane]);
        }
    }
}

extern "C" void kernel_launch(void* const* d_in, const int* in_sizes, int n_in,
                              void* d_out, int out_size, void* d_ws, size_t ws_size,
                              hipStream_t stream) {
    const float* z = (const float*)d_in[0];
    const long long n    = in_sizes[0];     // 33554432
    const long long rows = n / 16;          // 2097152

    float* out   = (float*)d_out;
    float* zq    = out;
    float* loss  = out + n;
    float* idx   = out + n + 1;
    float* avgp  = out + n + 1 + rows;

    const int NB = 2048;
    float* ws_h = (float*)d_ws;             // NB floats
    float* ws_p = ws_h + NB;                // 16*NB floats (total ~139 KB << ws_size)

    bsq_main<<<NB, 256, 0, stream>>>(z, zq, idx, ws_h, ws_p, rows);
    bsq_final<<<1, 1024, 0, stream>>>(ws_h, ws_p, loss, avgp, NB, rows);
}

// Round 4
// 72.221 us; speedup vs baseline: 1.9136x; 1.9136x over previous
//
#include <hip/hip_runtime.h>
#include <math.h>

// BinarySphericalQuantizer forward, EMBED_DIM=16, all scalars = 1.
// Outputs concatenated in d_out (float32):
//   [0, n)                : zq = sign(z)*0.25            (n = 33554432)
//   [n]                   : loss = persample_entropy - cb_entropy
//   [n+1, n+1+rows)       : indices (bit-packed signs), as float
//   [n+1+rows, +32)       : avg_prob (16 x 2)
//
// Layout: 4 lanes per row, one contiguous float4 per lane -> every wave
// load/store is 1KB contiguous (round-2 pattern; round-3's 64B-stride
// row-per-lane caused 2.3x write amplification).
// Math: s = z/||z||, |s|<=1; sigmoid/entropy via short polynomials in t=s^2
// (round-3 pattern; cut VALUBusy 42% -> 9%):
//   p - 1/2 = s*(D0 + D1 t + D2 t^2 + D3 t^3)     max err ~2e-5
//   H - ln2 = t*(C1 + C2 t + C3 t^2 + C4 t^3)     max err ~2e-5
// Constant parts (16*ln2 per row, +1/2 per prob) added exactly in finisher.
// Cross-lane (row norm, bit pack) via DPP quad_perm (full-rate VALU).

__device__ __forceinline__ float dpp_qxor1_f(float x) {
    return __int_as_float(__builtin_amdgcn_mov_dpp(__float_as_int(x), 0xB1, 0xF, 0xF, true));
}
__device__ __forceinline__ float dpp_qxor2_f(float x) {
    return __int_as_float(__builtin_amdgcn_mov_dpp(__float_as_int(x), 0x4E, 0xF, 0xF, true));
}
__device__ __forceinline__ unsigned dpp_qxor1_u(unsigned x) {
    return (unsigned)__builtin_amdgcn_mov_dpp((int)x, 0xB1, 0xF, 0xF, true);
}
__device__ __forceinline__ unsigned dpp_qxor2_u(unsigned x) {
    return (unsigned)__builtin_amdgcn_mov_dpp((int)x, 0x4E, 0xF, 0xF, true);
}

__global__ __launch_bounds__(256) void bsq_main(
    const float* __restrict__ z,
    float* __restrict__ zq,
    float* __restrict__ idx_out,
    float* __restrict__ ws_h,      // [gridDim.x] partials of sum(H - ln2)
    float* __restrict__ ws_p,      // [16][gridDim.x] partials of sum(p - 1/2)
    long long quads)               // n/4
{
    const int tid = threadIdx.x;
    const long long stride = (long long)gridDim.x * blockDim.x;
    const int c = tid & 3;         // quad position within row

    const float C1 = -0.125f, C2 = 1.0f/64.0f, C3 = -1.0f/576.0f, C4 = 119.0f/645120.0f;
    const float D0 = -0.25f,  D1 = 1.0f/48.0f, D2 = -1.0f/480.0f, D3 = 17.0f/80640.0f;

    float h_acc = 0.f;
    float p_acc[4] = {0.f, 0.f, 0.f, 0.f};

    for (long long q = (long long)blockIdx.x * blockDim.x + tid; q < quads; q += stride) {
        const float4 v = reinterpret_cast<const float4*>(z)[q];
        float vv[4] = {v.x, v.y, v.z, v.w};

        float ss = 0.f;
        #pragma unroll
        for (int j = 0; j < 4; ++j) ss = fmaf(vv[j], vv[j], ss);
        ss += dpp_qxor1_f(ss);                 // sum over the 4 lanes of this row
        ss += dpp_qxor2_f(ss);
        const float scale = rsqrtf(fmaxf(ss, 1e-24f));   // == 1/max(||z||,1e-12)

        unsigned bits = 0u;
        float4 o;
        float* op = &o.x;
        #pragma unroll
        for (int j = 0; j < 4; ++j) {
            const float s = vv[j] * scale;
            const float t = s * s;
            const float gp = fmaf(t, fmaf(t, fmaf(t, D3, D2), D1), D0);   // p - 1/2 = s*gp
            p_acc[j] = fmaf(s, gp, p_acc[j]);
            const float hin = fmaf(t, fmaf(t, fmaf(t, C4, C3), C2), C1);  // H - ln2 = t*hin
            h_acc = fmaf(t, hin, h_acc);

            const bool bit = vv[j] > 0.0f;
            op[j] = bit ? 0.25f : -0.25f;
            bits |= (bit ? 1u : 0u) << (15 - (4 * c + j));
        }
        reinterpret_cast<float4*>(zq)[q] = o;

        bits |= dpp_qxor1_u(bits);
        bits |= dpp_qxor2_u(bits);
        if (c == 0) idx_out[q >> 2] = (float)bits;   // <= 65535, exact in f32
    }

    // end-of-kernel reductions (cold path)
    // h over all 64 lanes; p over the 16 lanes sharing (lane&3)
    #pragma unroll
    for (int m = 32; m >= 4; m >>= 1) {
        h_acc += __shfl_xor(h_acc, m);
        #pragma unroll
        for (int j = 0; j < 4; ++j) p_acc[j] += __shfl_xor(p_acc[j], m);
    }
    h_acc += __shfl_xor(h_acc, 2);
    h_acc += __shfl_xor(h_acc, 1);

    __shared__ float sh_h[4];
    __shared__ float sh_p[4][16];
    const int wave = tid >> 6;
    const int lane = tid & 63;
    if (lane == 0) sh_h[wave] = h_acc;
    if (lane < 4) {
        #pragma unroll
        for (int j = 0; j < 4; ++j) sh_p[wave][4 * lane + j] = p_acc[j];
    }
    __syncthreads();

    if (tid == 0)
        ws_h[blockIdx.x] = sh_h[0] + sh_h[1] + sh_h[2] + sh_h[3];
    if (tid < 16)
        ws_p[(long long)tid * gridDim.x + blockIdx.x] =
            sh_p[0][tid] + sh_p[1][tid] + sh_p[2][tid] + sh_p[3][tid];
}

// 16 waves: wave w reduces p-group w; wave 0 also reduces h.
__global__ __launch_bounds__(1024) void bsq_final(
    const float* __restrict__ ws_h,
    const float* __restrict__ ws_p,
    float* __restrict__ loss_out,
    float* __restrict__ avgp_out,
    int nb, long long rows)
{
    const int tid  = threadIdx.x;
    const int wave = tid >> 6;     // 0..15
    const int lane = tid & 63;
    const double invR = 1.0 / (double)rows;
    const double LN2 = 0.6931471805599453;

    __shared__ double sh_q[16];
    __shared__ double sh_h;

    double p = 0.0;
    for (int i = lane; i < nb; i += 64)
        p += (double)ws_p[(long long)wave * nb + i];

    double h = 0.0;
    if (wave == 0)
        for (int i = lane; i < nb; i += 64)
            h += (double)ws_h[i];

    #pragma unroll
    for (int m = 32; m >= 1; m >>= 1)
        p += __shfl_xor(p, m);
    if (wave == 0) {
        #pragma unroll
        for (int m = 32; m >= 1; m >>= 1)
            h += __shfl_xor(h, m);
        if (lane == 0) sh_h = 16.0 * LN2 + h * invR;   // persample entropy
    }
    if (lane == 0) sh_q[wave] = 0.5 + p * invR;        // avg_prob[g][0]
    __syncthreads();

    if (wave == 0) {
        const double q = (lane < 16) ? sh_q[lane] : 0.0;
        double term = 0.0;
        if (lane < 16)
            term = -(q * log(q + 1e-8) + (1.0 - q) * log((1.0 - q) + 1e-8));
        #pragma unroll
        for (int m = 32; m >= 1; m >>= 1)
            term += __shfl_xor(term, m);
        if (lane == 0)
            loss_out[0] = (float)(sh_h - term);   // GAMMA0=GAMMA=ZETA=INV_T=1
        if (lane < 16) {
            avgp_out[2 * lane]     = (float)sh_q[lane];
            avgp_out[2 * lane + 1] = (float)(1.0 - sh_q[lane]);
        }
    }
}

extern "C" void kernel_launch(void* const* d_in, const int* in_sizes, int n_in,
                              void* d_out, int out_size, void* d_ws, size_t ws_size,
                              hipStream_t stream) {
    const float* z = (const float*)d_in[0];
    const long long n     = in_sizes[0];    // 33554432
    const long long rows  = n / 16;         // 2097152
    const long long quads = n / 4;          // 8388608

    float* out   = (float*)d_out;
    float* zq    = out;
    float* loss  = out + n;
    float* idx   = out + n + 1;
    float* avgp  = out + n + 1 + rows;

    const int NB = 2048;
    float* ws_h = (float*)d_ws;             // NB floats
    float* ws_p = ws_h + NB;                // 16*NB floats (total ~139 KB << ws_size)

    bsq_main<<<NB, 256, 0, stream>>>(z, zq, idx, ws_h, ws_p, quads);
    bsq_final<<<1, 1024, 0, stream>>>(ws_h, ws_p, loss, avgp, NB, rows);
}

// Round 5
// 67.887 us; speedup vs baseline: 2.0357x; 1.0638x over previous
//
#include <hip/hip_runtime.h>
#include <math.h>

// BinarySphericalQuantizer forward, EMBED_DIM=16, all scalars = 1.
// Outputs concatenated in d_out (float32):
//   [0, n)                : zq = sign(z)*0.25            (n = 33554432)
//   [n]                   : loss = persample_entropy - cb_entropy
//   [n+1, n+1+rows)       : indices (bit-packed signs), as float
//   [n+1+rows, +32)       : avg_prob (16 x 2)
//
// Layout: 4 lanes per row, one contiguous float4 per lane -> every wave
// load/store is 1KB contiguous. Cross-lane (norm, bitpack) via DPP quad_perm.
// Math: s = z/||z||, |s|<=1; sigmoid/entropy via polynomials in t=s^2
// (max err ~2e-5, only affects loss/avg_prob; thresholds ~1e-2).
// NT stores for zq/idx: they're write-once streams -> keep z L3-resident
// across replays (round-2 counters showed cached writes evicting z).
// 2-way unroll: two independent rows' quads in flight per iteration.

typedef float f32x4 __attribute__((ext_vector_type(4)));

__device__ __forceinline__ float dpp_qxor1_f(float x) {
    return __int_as_float(__builtin_amdgcn_mov_dpp(__float_as_int(x), 0xB1, 0xF, 0xF, true));
}
__device__ __forceinline__ float dpp_qxor2_f(float x) {
    return __int_as_float(__builtin_amdgcn_mov_dpp(__float_as_int(x), 0x4E, 0xF, 0xF, true));
}
__device__ __forceinline__ unsigned dpp_qxor1_u(unsigned x) {
    return (unsigned)__builtin_amdgcn_mov_dpp((int)x, 0xB1, 0xF, 0xF, true);
}
__device__ __forceinline__ unsigned dpp_qxor2_u(unsigned x) {
    return (unsigned)__builtin_amdgcn_mov_dpp((int)x, 0x4E, 0xF, 0xF, true);
}

__device__ __forceinline__ void process_quad(
    const float4 v, const int c,
    float& h_acc, float* p_acc, f32x4& o, unsigned& bits)
{
    const float C1 = -0.125f, C2 = 1.0f/64.0f, C3 = -1.0f/576.0f, C4 = 119.0f/645120.0f;
    const float D0 = -0.25f,  D1 = 1.0f/48.0f, D2 = -1.0f/480.0f, D3 = 17.0f/80640.0f;

    float vv[4] = {v.x, v.y, v.z, v.w};

    float ss = 0.f;
    #pragma unroll
    for (int j = 0; j < 4; ++j) ss = fmaf(vv[j], vv[j], ss);
    ss += dpp_qxor1_f(ss);                  // sum over the 4 lanes of this row
    ss += dpp_qxor2_f(ss);
    const float scale = rsqrtf(fmaxf(ss, 1e-24f));   // == 1/max(||z||,1e-12)

    bits = 0u;
    #pragma unroll
    for (int j = 0; j < 4; ++j) {
        const float s = vv[j] * scale;
        const float t = s * s;
        const float gp = fmaf(t, fmaf(t, fmaf(t, D3, D2), D1), D0);   // p-1/2 = s*gp
        p_acc[j] = fmaf(s, gp, p_acc[j]);
        const float hin = fmaf(t, fmaf(t, fmaf(t, C4, C3), C2), C1);  // H-ln2 = t*hin
        h_acc = fmaf(t, hin, h_acc);

        const bool bit = vv[j] > 0.0f;
        o[j] = bit ? 0.25f : -0.25f;
        bits |= (bit ? 1u : 0u) << (15 - (4 * c + j));
    }
    bits |= dpp_qxor1_u(bits);
    bits |= dpp_qxor2_u(bits);
}

__global__ __launch_bounds__(256) void bsq_main(
    const float* __restrict__ z,
    float* __restrict__ zq,
    float* __restrict__ idx_out,
    float* __restrict__ ws_h,      // [gridDim.x] partials of sum(H - ln2)
    float* __restrict__ ws_p,      // [16][gridDim.x] partials of sum(p - 1/2)
    long long quads)               // n/4
{
    const int tid = threadIdx.x;
    const long long stride = (long long)gridDim.x * blockDim.x;
    const int c = tid & 3;         // quad position within row

    float h_acc = 0.f;
    float p_acc[4] = {0.f, 0.f, 0.f, 0.f};

    long long q = (long long)blockIdx.x * blockDim.x + tid;

    // 2-deep: two independent rows' quads in flight
    for (; q + stride < quads; q += 2 * stride) {
        const float4 va = reinterpret_cast<const float4*>(z)[q];
        const float4 vb = reinterpret_cast<const float4*>(z)[q + stride];

        f32x4 oa, ob;
        unsigned ba, bb;
        process_quad(va, c, h_acc, p_acc, oa, ba);
        process_quad(vb, c, h_acc, p_acc, ob, bb);

        __builtin_nontemporal_store(oa, reinterpret_cast<f32x4*>(zq) + q);
        __builtin_nontemporal_store(ob, reinterpret_cast<f32x4*>(zq) + q + stride);
        if (c == 0) {
            __builtin_nontemporal_store((float)ba, idx_out + (q >> 2));
            __builtin_nontemporal_store((float)bb, idx_out + ((q + stride) >> 2));
        }
    }
    for (; q < quads; q += stride) {
        const float4 v = reinterpret_cast<const float4*>(z)[q];
        f32x4 o; unsigned b;
        process_quad(v, c, h_acc, p_acc, o, b);
        __builtin_nontemporal_store(o, reinterpret_cast<f32x4*>(zq) + q);
        if (c == 0) __builtin_nontemporal_store((float)b, idx_out + (q >> 2));
    }

    // end-of-kernel reductions (cold path)
    // h over all 64 lanes; p over the 16 lanes sharing (lane&3)
    #pragma unroll
    for (int m = 32; m >= 4; m >>= 1) {
        h_acc += __shfl_xor(h_acc, m);
        #pragma unroll
        for (int j = 0; j < 4; ++j) p_acc[j] += __shfl_xor(p_acc[j], m);
    }
    h_acc += __shfl_xor(h_acc, 2);
    h_acc += __shfl_xor(h_acc, 1);

    __shared__ float sh_h[4];
    __shared__ float sh_p[4][16];
    const int wave = tid >> 6;
    const int lane = tid & 63;
    if (lane == 0) sh_h[wave] = h_acc;
    if (lane < 4) {
        #pragma unroll
        for (int j = 0; j < 4; ++j) sh_p[wave][4 * lane + j] = p_acc[j];
    }
    __syncthreads();

    if (tid == 0)
        ws_h[blockIdx.x] = sh_h[0] + sh_h[1] + sh_h[2] + sh_h[3];
    if (tid < 16)
        ws_p[(long long)tid * gridDim.x + blockIdx.x] =
            sh_p[0][tid] + sh_p[1][tid] + sh_p[2][tid] + sh_p[3][tid];
}

// 16 waves: wave w reduces p-group w; wave 0 also reduces h.
__global__ __launch_bounds__(1024) void bsq_final(
    const float* __restrict__ ws_h,
    const float* __restrict__ ws_p,
    float* __restrict__ loss_out,
    float* __restrict__ avgp_out,
    int nb, long long rows)
{
    const int tid  = threadIdx.x;
    const int wave = tid >> 6;     // 0..15
    const int lane = tid & 63;
    const double invR = 1.0 / (double)rows;
    const double LN2 = 0.6931471805599453;

    __shared__ double sh_q[16];
    __shared__ double sh_h;

    double p = 0.0;
    for (int i = lane; i < nb; i += 64)
        p += (double)ws_p[(long long)wave * nb + i];

    double h = 0.0;
    if (wave == 0)
        for (int i = lane; i < nb; i += 64)
            h += (double)ws_h[i];

    #pragma unroll
    for (int m = 32; m >= 1; m >>= 1)
        p += __shfl_xor(p, m);
    if (wave == 0) {
        #pragma unroll
        for (int m = 32; m >= 1; m >>= 1)
            h += __shfl_xor(h, m);
        if (lane == 0) sh_h = 16.0 * LN2 + h * invR;   // persample entropy
    }
    if (lane == 0) sh_q[wave] = 0.5 + p * invR;        // avg_prob[g][0]
    __syncthreads();

    if (wave == 0) {
        const double q = (lane < 16) ? sh_q[lane] : 0.0;
        double term = 0.0;
        if (lane < 16)
            term = -(q * log(q + 1e-8) + (1.0 - q) * log((1.0 - q) + 1e-8));
        #pragma unroll
        for (int m = 32; m >= 1; m >>= 1)
            term += __shfl_xor(term, m);
        if (lane == 0)
            loss_out[0] = (float)(sh_h - term);   // GAMMA0=GAMMA=ZETA=INV_T=1
        if (lane < 16) {
            avgp_out[2 * lane]     = (float)sh_q[lane];
            avgp_out[2 * lane + 1] = (float)(1.0 - sh_q[lane]);
        }
    }
}

extern "C" void kernel_launch(void* const* d_in, const int* in_sizes, int n_in,
                              void* d_out, int out_size, void* d_ws, size_t ws_size,
                              hipStream_t stream) {
    const float* z = (const float*)d_in[0];
    const long long n     = in_sizes[0];    // 33554432
    const long long rows  = n / 16;         // 2097152
    const long long quads = n / 4;          // 8388608

    float* out   = (float*)d_out;
    float* zq    = out;
    float* loss  = out + n;
    float* idx   = out + n + 1;
    float* avgp  = out + n + 1 + rows;

    const int NB = 2048;
    float* ws_h = (float*)d_ws;             // NB floats
    float* ws_p = ws_h + NB;                // 16*NB floats (total ~139 KB << ws_size)

    bsq_main<<<NB, 256, 0, stream>>>(z, zq, idx, ws_h, ws_p, quads);
    bsq_final<<<1, 1024, 0, stream>>>(ws_h, ws_p, loss, avgp, NB, rows);
}